// Round 1
// baseline (941.926 us; speedup 1.0000x reference)
//
#include <hip/hip_runtime.h>

#define IN_DIM 256
#define HID 64
#define LAT 32
#define EPS 1e-5f
#define THREADS 256

static inline int cdiv(int a, int b){ return (a + b - 1) / b; }

// ---------- init: deg=1 (self loop), cnt=0, stats=0 ----------
__global__ void k_init(float* __restrict__ deg, int* __restrict__ cnt,
                       float* __restrict__ stats, int n){
  int i = blockIdx.x * blockDim.x + threadIdx.x;
  if (i < n){ deg[i] = 1.0f; cnt[i] = 0; }
  if (i < 192) stats[i] = 0.0f;
}

// ---------- degree + in-edge count ----------
__global__ void k_count(const int* __restrict__ ei, const float* __restrict__ ew,
                        float* __restrict__ deg, int* __restrict__ cnt, int E){
  int e = blockIdx.x * blockDim.x + threadIdx.x;
  if (e >= E) return;
  int c = ei[E + e];
  atomicAdd(&deg[c], ew[e]);
  atomicAdd(&cnt[c], 1);
}

// ---------- dinv = rsqrt(deg) in place (deg >= 1 always) ----------
__global__ void k_dinv(float* __restrict__ deg, int n){
  int i = blockIdx.x * blockDim.x + threadIdx.x;
  if (i < n) deg[i] = rsqrtf(deg[i]);
}

// ---------- exclusive scan of cnt -> offs (3 kernels) ----------
__global__ void k_scan1(const int* __restrict__ cnt, int* __restrict__ offs,
                        int* __restrict__ bsum, int n){
  __shared__ int lds[256];
  int t = threadIdx.x, b = blockIdx.x;
  int base = b * 2048 + t * 8;
  int v[8]; int s = 0;
  #pragma unroll
  for (int k = 0; k < 8; k++){ int idx = base + k; v[k] = (idx < n) ? cnt[idx] : 0; s += v[k]; }
  lds[t] = s; __syncthreads();
  for (int d = 1; d < 256; d <<= 1){
    int xv = (t >= d) ? lds[t - d] : 0;
    __syncthreads();
    lds[t] += xv;
    __syncthreads();
  }
  int excl = lds[t] - s;
  #pragma unroll
  for (int k = 0; k < 8; k++){ int idx = base + k; if (idx < n) offs[idx] = excl; excl += v[k]; }
  if (t == 0) bsum[b] = lds[255];
}

__global__ void k_scan2(int* __restrict__ bsum, int nb){
  __shared__ int lds[64];
  int t = threadIdx.x;
  int s = (t < nb) ? bsum[t] : 0;
  lds[t] = s; __syncthreads();
  for (int d = 1; d < 64; d <<= 1){
    int xv = (t >= d) ? lds[t - d] : 0;
    __syncthreads();
    lds[t] += xv;
    __syncthreads();
  }
  if (t < nb) bsum[t] = lds[t] - s;
}

__global__ void k_scan3(int* __restrict__ offs, int* __restrict__ cur,
                        const int* __restrict__ bsum, int n){
  int i = blockIdx.x * blockDim.x + threadIdx.x;
  if (i >= n) return;
  int o = offs[i] + bsum[i >> 11];
  offs[i] = o; cur[i] = o;
}

// ---------- fill CSR (order within bucket irrelevant for sum) ----------
__global__ void k_fill(const int* __restrict__ ei, const float* __restrict__ ew,
                       const float* __restrict__ dinv, int* __restrict__ cur,
                       int* __restrict__ srcs, float* __restrict__ vals, int E){
  int e = blockIdx.x * blockDim.x + threadIdx.x;
  if (e >= E) return;
  int r = ei[e], c = ei[E + e];
  int pos = atomicAdd(&cur[c], 1);
  srcs[pos] = r;
  vals[pos] = dinv[r] * ew[e] * dinv[c];
}

// ---------- fused GEMM: h1 = x@W1 ; xin = x@Wr + br ----------
__global__ __launch_bounds__(THREADS) void k_gemm1(
    const float* __restrict__ x, const float* __restrict__ W1,
    const float* __restrict__ Wr, const float* __restrict__ br,
    float* __restrict__ h1, float* __restrict__ xin, int n){
  int row = blockIdx.x * blockDim.x + threadIdx.x;
  if (row >= n) return;
  float a1[HID], a2[LAT];
  #pragma unroll
  for (int c = 0; c < HID; c++) a1[c] = 0.f;
  #pragma unroll
  for (int c = 0; c < LAT; c++) a2[c] = 0.f;
  const float4* xr = (const float4*)(x + (size_t)row * IN_DIM);
  for (int k4 = 0; k4 < IN_DIM / 4; k4++){
    float4 xv = xr[k4];
    float xs[4] = {xv.x, xv.y, xv.z, xv.w};
    #pragma unroll
    for (int j = 0; j < 4; j++){
      int k = k4 * 4 + j;
      const float* w1 = W1 + k * HID;
      const float* wr = Wr + k * LAT;
      #pragma unroll
      for (int c = 0; c < HID; c++) a1[c] = fmaf(xs[j], w1[c], a1[c]);
      #pragma unroll
      for (int c = 0; c < LAT; c++) a2[c] = fmaf(xs[j], wr[c], a2[c]);
    }
  }
  float* h1r = h1 + (size_t)row * HID;
  #pragma unroll
  for (int c = 0; c < HID; c += 4)
    *(float4*)(h1r + c) = make_float4(a1[c], a1[c+1], a1[c+2], a1[c+3]);
  float* xo = xin + (size_t)row * LAT;
  #pragma unroll
  for (int c = 0; c < LAT; c += 4)
    *(float4*)(xo + c) = make_float4(a2[c] + br[c], a2[c+1] + br[c+1],
                                     a2[c+2] + br[c+2], a2[c+3] + br[c+3]);
}

// ---------- aggregation: out[i,f] = sum_j vals[j]*h[srcs[j],f] + dinv[i]^2 * h[i,f] ----------
template<int F>
__global__ void k_agg(const float* __restrict__ h, const int* __restrict__ offs,
                      const int* __restrict__ cnt, const int* __restrict__ srcs,
                      const float* __restrict__ vals, const float* __restrict__ dinv,
                      float* __restrict__ out, int n){
  int gt = blockIdx.x * blockDim.x + threadIdx.x;
  int node = gt / F;
  int lane = gt & (F - 1);
  if (node >= n) return;
  float di = dinv[node];
  float acc = h[(size_t)node * F + lane] * (di * di);
  int j = offs[node];
  int e = j + cnt[node];
  for (; j + 3 < e; j += 4){
    int s0 = srcs[j], s1 = srcs[j+1], s2 = srcs[j+2], s3 = srcs[j+3];
    float v0 = vals[j], v1 = vals[j+1], v2 = vals[j+2], v3 = vals[j+3];
    acc = fmaf(h[(size_t)s0 * F + lane], v0, acc);
    acc = fmaf(h[(size_t)s1 * F + lane], v1, acc);
    acc = fmaf(h[(size_t)s2 * F + lane], v2, acc);
    acc = fmaf(h[(size_t)s3 * F + lane], v3, acc);
  }
  for (; j < e; j++)
    acc = fmaf(h[(size_t)srcs[j] * F + lane], vals[j], acc);
  out[(size_t)node * F + lane] = acc;
}

// ---------- batchnorm stats: per-feature sum & sumsq ----------
template<int F>
__global__ void k_bnstats(const float* __restrict__ a, float* __restrict__ sums,
                          float* __restrict__ sqs, int n){
  __shared__ float ls[256], lq[256];
  int t = threadIdx.x;
  int f = t & (F - 1);
  const int rpb = 256 / F;
  int r = blockIdx.x * rpb + t / F;
  int stride = gridDim.x * rpb;
  float s = 0.f, q = 0.f;
  for (; r < n; r += stride){
    float v = a[(size_t)r * F + f];
    s += v; q += v * v;
  }
  ls[t] = s; lq[t] = q; __syncthreads();
  if (t < F){
    for (int j = t + F; j < 256; j += F){ s += ls[j]; q += lq[j]; }
    atomicAdd(&sums[f], s);
    atomicAdd(&sqs[f], q);
  }
}

// ---------- finalize BN affine: scale/shift (bias b cancels in BN) ----------
__global__ void k_bnfin(const float* __restrict__ sums, const float* __restrict__ sqs,
                        const float* __restrict__ g, const float* __restrict__ be,
                        float* __restrict__ scale, float* __restrict__ shift,
                        int n, int F){
  int f = threadIdx.x;
  if (f >= F) return;
  float inv_n = 1.0f / (float)n;
  float mean = sums[f] * inv_n;
  float var = sqs[f] * inv_n - mean * mean;
  float sc = g[f] * rsqrtf(var + EPS);
  scale[f] = sc;
  shift[f] = be[f] - mean * sc;
}

// ---------- fused BN1 + PReLU + GEMM2: h2 = prelu(bn(agg1)) @ W2 ----------
__global__ __launch_bounds__(THREADS) void k_gemm2(
    const float* __restrict__ agg1, const float* __restrict__ scale,
    const float* __restrict__ shift, const float* __restrict__ prelu_a,
    const float* __restrict__ W2, float* __restrict__ h2, int n){
  int row = blockIdx.x * blockDim.x + threadIdx.x;
  if (row >= n) return;
  float al = prelu_a[0];
  float y[HID];
  const float4* ar = (const float4*)(agg1 + (size_t)row * HID);
  #pragma unroll
  for (int k4 = 0; k4 < HID / 4; k4++){
    float4 v = ar[k4];
    float vv[4] = {v.x, v.y, v.z, v.w};
    #pragma unroll
    for (int j = 0; j < 4; j++){
      int k = k4 * 4 + j;
      float t = vv[j] * scale[k] + shift[k];
      y[k] = (t >= 0.f) ? t : al * t;
    }
  }
  float acc[LAT];
  #pragma unroll
  for (int c = 0; c < LAT; c++) acc[c] = 0.f;
  for (int k = 0; k < HID; k++){
    const float* w = W2 + k * LAT;
    #pragma unroll
    for (int c = 0; c < LAT; c++) acc[c] = fmaf(y[k], w[c], acc[c]);
  }
  float* hr = h2 + (size_t)row * LAT;
  #pragma unroll
  for (int c = 0; c < LAT; c += 4)
    *(float4*)(hr + c) = make_float4(acc[c], acc[c+1], acc[c+2], acc[c+3]);
}

// ---------- final: out = bn2(agg2) + xin ----------
__global__ void k_final(const float* __restrict__ agg2, const float* __restrict__ scale,
                        const float* __restrict__ shift, const float* __restrict__ xin,
                        float* __restrict__ out, int n){
  int i = blockIdx.x * blockDim.x + threadIdx.x; // over n*LAT/4 float4s
  int total = n * (LAT / 4);
  if (i >= total) return;
  float4 a = ((const float4*)agg2)[i];
  float4 xi = ((const float4*)xin)[i];
  int f = (i * 4) & (LAT - 1);
  float4 o;
  o.x = a.x * scale[f+0] + shift[f+0] + xi.x;
  o.y = a.y * scale[f+1] + shift[f+1] + xi.y;
  o.z = a.z * scale[f+2] + shift[f+2] + xi.z;
  o.w = a.w * scale[f+3] + shift[f+3] + xi.w;
  ((float4*)out)[i] = o;
}

extern "C" void kernel_launch(void* const* d_in, const int* in_sizes, int n_in,
                              void* d_out, int out_size, void* d_ws, size_t ws_size,
                              hipStream_t stream){
  const float* x   = (const float*)d_in[0];
  const int*   ei  = (const int*)d_in[1];
  const float* ew  = (const float*)d_in[2];
  const float* W1  = (const float*)d_in[3];
  const float* g1  = (const float*)d_in[5];
  const float* be1 = (const float*)d_in[6];
  const float* W2  = (const float*)d_in[7];
  const float* g2  = (const float*)d_in[9];
  const float* be2 = (const float*)d_in[10];
  const float* pa  = (const float*)d_in[11];
  const float* Wr  = (const float*)d_in[12];
  const float* br  = (const float*)d_in[13];
  float* out = (float*)d_out;

  const int N = in_sizes[0] / IN_DIM;
  const int E = in_sizes[2];

  // workspace layout (256B aligned)
  char* ws = (char*)d_ws;
  size_t o = 0;
  auto alloc = [&](size_t bytes)->char*{
    char* p = ws + o;
    o = (o + bytes + 255) & ~(size_t)255;
    return p;
  };
  float* deg   = (float*)alloc((size_t)N * 4);      // becomes dinv
  int*   cnt   = (int*)  alloc((size_t)N * 4);
  int*   offs  = (int*)  alloc((size_t)N * 4);
  int*   cur   = (int*)  alloc((size_t)N * 4);
  int*   bsum  = (int*)  alloc(64 * 4);
  float* stats = (float*)alloc(192 * 4);  // sums1[64] sqs1[64] sums2[32] sqs2[32]
  float* coef  = (float*)alloc(192 * 4);  // scale1[64] shift1[64] scale2[32] shift2[32]
  int*   srcs  = (int*)  alloc((size_t)E * 4);
  float* vals  = (float*)alloc((size_t)E * 4);
  float* bufA  = (float*)alloc((size_t)N * HID * 4); // h1, then h2
  float* bufB  = (float*)alloc((size_t)N * HID * 4); // agg1, then agg2
  float* xin   = (float*)alloc((size_t)N * LAT * 4);

  float* sums1 = stats, *sqs1 = stats + 64, *sums2 = stats + 128, *sqs2 = stats + 160;
  float* sc1 = coef, *sh1 = coef + 64, *sc2 = coef + 128, *sh2 = coef + 160;

  const int NB = cdiv(N, 2048);

  k_init<<<cdiv(N, THREADS), THREADS, 0, stream>>>(deg, cnt, stats, N);
  k_count<<<cdiv(E, THREADS), THREADS, 0, stream>>>(ei, ew, deg, cnt, E);
  k_dinv<<<cdiv(N, THREADS), THREADS, 0, stream>>>(deg, N);
  k_scan1<<<NB, 256, 0, stream>>>(cnt, offs, bsum, N);
  k_scan2<<<1, 64, 0, stream>>>(bsum, NB);
  k_scan3<<<cdiv(N, THREADS), THREADS, 0, stream>>>(offs, cur, bsum, N);
  k_fill<<<cdiv(E, THREADS), THREADS, 0, stream>>>(ei, ew, deg, cur, srcs, vals, E);

  k_gemm1<<<cdiv(N, THREADS), THREADS, 0, stream>>>(x, W1, Wr, br, bufA, xin, N);
  k_agg<HID><<<cdiv(N * HID, THREADS), THREADS, 0, stream>>>(bufA, offs, cnt, srcs, vals, deg, bufB, N);
  k_bnstats<HID><<<256, 256, 0, stream>>>(bufB, sums1, sqs1, N);
  k_bnfin<<<1, 64, 0, stream>>>(sums1, sqs1, g1, be1, sc1, sh1, N, HID);
  k_gemm2<<<cdiv(N, THREADS), THREADS, 0, stream>>>(bufB, sc1, sh1, pa, W2, bufA, N);
  k_agg<LAT><<<cdiv(N * LAT, THREADS), THREADS, 0, stream>>>(bufA, offs, cnt, srcs, vals, deg, bufB, N);
  k_bnstats<LAT><<<256, 256, 0, stream>>>(bufB, sums2, sqs2, N);
  k_bnfin<<<1, 32, 0, stream>>>(sums2, sqs2, g2, be2, sc2, sh2, N, LAT);
  k_final<<<cdiv(N * LAT / 4, THREADS), THREADS, 0, stream>>>(bufB, sc2, sh2, xin, out, N);
}

// Round 2
// 752.424 us; speedup vs baseline: 1.2519x; 1.2519x over previous
//
#include <hip/hip_runtime.h>

#define IN_DIM 256
#define HID 64
#define LAT 32
#define EPS 1e-5f
#define THREADS 256

static inline int cdiv(int a, int b){ return (a + b - 1) / b; }

// ---------- init: deg=1 (self loop), cnt=0, stats=0 ----------
__global__ void k_init(float* __restrict__ deg, int* __restrict__ cnt,
                       float* __restrict__ stats, int n){
  int i = blockIdx.x * blockDim.x + threadIdx.x;
  if (i < n){ deg[i] = 1.0f; cnt[i] = 0; }
  if (i < 192) stats[i] = 0.0f;
}

// ---------- degree + in-edge count ----------
__global__ void k_count(const int* __restrict__ ei, const float* __restrict__ ew,
                        float* __restrict__ deg, int* __restrict__ cnt, int E){
  int e = blockIdx.x * blockDim.x + threadIdx.x;
  if (e >= E) return;
  int c = ei[E + e];
  atomicAdd(&deg[c], ew[e]);
  atomicAdd(&cnt[c], 1);
}

// ---------- dinv = rsqrt(deg) in place (deg >= 1 always) ----------
__global__ void k_dinv(float* __restrict__ deg, int n){
  int i = blockIdx.x * blockDim.x + threadIdx.x;
  if (i < n) deg[i] = rsqrtf(deg[i]);
}

// ---------- exclusive scan of cnt -> offs (3 kernels) ----------
__global__ void k_scan1(const int* __restrict__ cnt, int* __restrict__ offs,
                        int* __restrict__ bsum, int n){
  __shared__ int lds[256];
  int t = threadIdx.x, b = blockIdx.x;
  int base = b * 2048 + t * 8;
  int v[8]; int s = 0;
  #pragma unroll
  for (int k = 0; k < 8; k++){ int idx = base + k; v[k] = (idx < n) ? cnt[idx] : 0; s += v[k]; }
  lds[t] = s; __syncthreads();
  for (int d = 1; d < 256; d <<= 1){
    int xv = (t >= d) ? lds[t - d] : 0;
    __syncthreads();
    lds[t] += xv;
    __syncthreads();
  }
  int excl = lds[t] - s;
  #pragma unroll
  for (int k = 0; k < 8; k++){ int idx = base + k; if (idx < n) offs[idx] = excl; excl += v[k]; }
  if (t == 0) bsum[b] = lds[255];
}

__global__ void k_scan2(int* __restrict__ bsum, int nb){
  __shared__ int lds[64];
  int t = threadIdx.x;
  int s = (t < nb) ? bsum[t] : 0;
  lds[t] = s; __syncthreads();
  for (int d = 1; d < 64; d <<= 1){
    int xv = (t >= d) ? lds[t - d] : 0;
    __syncthreads();
    lds[t] += xv;
    __syncthreads();
  }
  if (t < nb) bsum[t] = lds[t] - s;
}

__global__ void k_scan3(int* __restrict__ offs, int* __restrict__ cur,
                        const int* __restrict__ bsum, int n){
  int i = blockIdx.x * blockDim.x + threadIdx.x;
  if (i >= n) return;
  int o = offs[i] + bsum[i >> 11];
  offs[i] = o; cur[i] = o;
}

// ---------- fill CSR (order within bucket irrelevant for sum) ----------
__global__ void k_fill(const int* __restrict__ ei, const float* __restrict__ ew,
                       const float* __restrict__ dinv, int* __restrict__ cur,
                       int* __restrict__ srcs, float* __restrict__ vals, int E){
  int e = blockIdx.x * blockDim.x + threadIdx.x;
  if (e >= E) return;
  int r = ei[e], c = ei[E + e];
  int pos = atomicAdd(&cur[c], 1);
  srcs[pos] = r;
  vals[pos] = dinv[r] * ew[e] * dinv[c];
}

// ---------- fused GEMM1: h1 = x@W1 ; xin = x@Wr + br ----------
// Wave-per-column-group register tiling: 6 waves x 16 cols, 64 rows/block.
// W (combined 96 cols) staged in LDS in K-halves of 128 -> 48KB, 2 blocks/CU.
// 16 accumulators/thread: no scratch spill (the round-0 killer).
#define G1_THREADS 384
__global__ __launch_bounds__(G1_THREADS) void k_gemm1(
    const float* __restrict__ x, const float* __restrict__ W1,
    const float* __restrict__ Wr, const float* __restrict__ br,
    float* __restrict__ h1, float* __restrict__ xin, int n){
  __shared__ float Wl[128][96];  // 49152 B
  int t = threadIdx.x;
  int wave = t >> 6, lane = t & 63;
  int row = blockIdx.x * 64 + lane;
  bool active = row < n;
  const float4* xr = (const float4*)(x + (size_t)row * IN_DIM);
  int c0 = wave * 16;
  float acc[16];
  #pragma unroll
  for (int i = 0; i < 16; i++) acc[i] = 0.f;

  for (int half = 0; half < 2; half++){
    // stage W1 half: 128 rows x 64 cols = 2048 float4
    for (int i = t; i < 2048; i += G1_THREADS){
      float4 v = ((const float4*)W1)[half * 2048 + i];
      int k = i >> 4, c = (i & 15) * 4;
      *(float4*)&Wl[k][c] = v;
    }
    // stage Wr half: 128 rows x 32 cols = 1024 float4
    for (int i = t; i < 1024; i += G1_THREADS){
      float4 v = ((const float4*)Wr)[half * 1024 + i];
      int k = i >> 3, c = (i & 7) * 4;
      *(float4*)&Wl[k][64 + c] = v;
    }
    __syncthreads();

    for (int k4 = 0; k4 < 32; k4++){
      float4 xv = active ? xr[half * 32 + k4] : make_float4(0.f,0.f,0.f,0.f);
      float xs[4] = {xv.x, xv.y, xv.z, xv.w};
      #pragma unroll
      for (int j = 0; j < 4; j++){
        const float* wrow = &Wl[k4 * 4 + j][c0];
        float4 wa = *(const float4*)(wrow);
        float4 wb = *(const float4*)(wrow + 4);
        float4 wc = *(const float4*)(wrow + 8);
        float4 wd = *(const float4*)(wrow + 12);
        float xj = xs[j];
        acc[ 0] = fmaf(xj, wa.x, acc[ 0]);
        acc[ 1] = fmaf(xj, wa.y, acc[ 1]);
        acc[ 2] = fmaf(xj, wa.z, acc[ 2]);
        acc[ 3] = fmaf(xj, wa.w, acc[ 3]);
        acc[ 4] = fmaf(xj, wb.x, acc[ 4]);
        acc[ 5] = fmaf(xj, wb.y, acc[ 5]);
        acc[ 6] = fmaf(xj, wb.z, acc[ 6]);
        acc[ 7] = fmaf(xj, wb.w, acc[ 7]);
        acc[ 8] = fmaf(xj, wc.x, acc[ 8]);
        acc[ 9] = fmaf(xj, wc.y, acc[ 9]);
        acc[10] = fmaf(xj, wc.z, acc[10]);
        acc[11] = fmaf(xj, wc.w, acc[11]);
        acc[12] = fmaf(xj, wd.x, acc[12]);
        acc[13] = fmaf(xj, wd.y, acc[13]);
        acc[14] = fmaf(xj, wd.z, acc[14]);
        acc[15] = fmaf(xj, wd.w, acc[15]);
      }
    }
    __syncthreads();
  }

  if (!active) return;
  if (wave < 4){
    float* p = h1 + (size_t)row * HID + c0;
    #pragma unroll
    for (int c = 0; c < 16; c += 4)
      *(float4*)(p + c) = make_float4(acc[c], acc[c+1], acc[c+2], acc[c+3]);
  } else {
    int cb = c0 - 64;
    float* p = xin + (size_t)row * LAT + cb;
    #pragma unroll
    for (int c = 0; c < 16; c += 4)
      *(float4*)(p + c) = make_float4(acc[c] + br[cb+c], acc[c+1] + br[cb+c+1],
                                      acc[c+2] + br[cb+c+2], acc[c+3] + br[cb+c+3]);
  }
}

// ---------- aggregation: out[i,f] = sum_j vals[j]*h[srcs[j],f] + dinv[i]^2 * h[i,f] ----------
template<int F>
__global__ void k_agg(const float* __restrict__ h, const int* __restrict__ offs,
                      const int* __restrict__ cnt, const int* __restrict__ srcs,
                      const float* __restrict__ vals, const float* __restrict__ dinv,
                      float* __restrict__ out, int n){
  int gt = blockIdx.x * blockDim.x + threadIdx.x;
  int node = gt / F;
  int lane = gt & (F - 1);
  if (node >= n) return;
  float di = dinv[node];
  float acc = h[(size_t)node * F + lane] * (di * di);
  int j = offs[node];
  int e = j + cnt[node];
  for (; j + 3 < e; j += 4){
    int s0 = srcs[j], s1 = srcs[j+1], s2 = srcs[j+2], s3 = srcs[j+3];
    float v0 = vals[j], v1 = vals[j+1], v2 = vals[j+2], v3 = vals[j+3];
    acc = fmaf(h[(size_t)s0 * F + lane], v0, acc);
    acc = fmaf(h[(size_t)s1 * F + lane], v1, acc);
    acc = fmaf(h[(size_t)s2 * F + lane], v2, acc);
    acc = fmaf(h[(size_t)s3 * F + lane], v3, acc);
  }
  for (; j < e; j++)
    acc = fmaf(h[(size_t)srcs[j] * F + lane], vals[j], acc);
  out[(size_t)node * F + lane] = acc;
}

// ---------- batchnorm stats: per-feature sum & sumsq ----------
template<int F>
__global__ void k_bnstats(const float* __restrict__ a, float* __restrict__ sums,
                          float* __restrict__ sqs, int n){
  __shared__ float ls[256], lq[256];
  int t = threadIdx.x;
  int f = t & (F - 1);
  const int rpb = 256 / F;
  int r = blockIdx.x * rpb + t / F;
  int stride = gridDim.x * rpb;
  float s = 0.f, q = 0.f;
  for (; r < n; r += stride){
    float v = a[(size_t)r * F + f];
    s += v; q += v * v;
  }
  ls[t] = s; lq[t] = q; __syncthreads();
  if (t < F){
    for (int j = t + F; j < 256; j += F){ s += ls[j]; q += lq[j]; }
    atomicAdd(&sums[f], s);
    atomicAdd(&sqs[f], q);
  }
}

// ---------- finalize BN affine: scale/shift (conv bias cancels in BN) ----------
__global__ void k_bnfin(const float* __restrict__ sums, const float* __restrict__ sqs,
                        const float* __restrict__ g, const float* __restrict__ be,
                        float* __restrict__ scale, float* __restrict__ shift,
                        int n, int F){
  int f = threadIdx.x;
  if (f >= F) return;
  float inv_n = 1.0f / (float)n;
  float mean = sums[f] * inv_n;
  float var = sqs[f] * inv_n - mean * mean;
  float sc = g[f] * rsqrtf(var + EPS);
  scale[f] = sc;
  shift[f] = be[f] - mean * sc;
}

// ---------- fused BN1 + PReLU + GEMM2: h2 = prelu(bn(agg1)) @ W2 ----------
// 4 waves x 8 cols, 64 rows/block; W2 + bn coefs in LDS; 8 accumulators/thread.
__global__ __launch_bounds__(THREADS) void k_gemm2(
    const float* __restrict__ agg1, const float* __restrict__ scale,
    const float* __restrict__ shift, const float* __restrict__ prelu_a,
    const float* __restrict__ W2, float* __restrict__ h2, int n){
  __shared__ float W2l[HID][LAT];   // 8KB
  __shared__ float scl[HID], shl[HID];
  int t = threadIdx.x;
  // stage W2: 64*32/4 = 512 float4
  for (int i = t; i < 512; i += THREADS){
    float4 v = ((const float4*)W2)[i];
    int k = i >> 3, c = (i & 7) * 4;
    *(float4*)&W2l[k][c] = v;
  }
  if (t < HID){ scl[t] = scale[t]; shl[t] = shift[t]; }
  __syncthreads();

  int wave = t >> 6, lane = t & 63;
  int row = blockIdx.x * 64 + lane;
  if (row >= n) return;
  float al = prelu_a[0];
  int c0 = wave * 8;
  const float4* ar = (const float4*)(agg1 + (size_t)row * HID);
  float acc[8];
  #pragma unroll
  for (int i = 0; i < 8; i++) acc[i] = 0.f;
  for (int k4 = 0; k4 < HID / 4; k4++){
    float4 av = ar[k4];
    float as[4] = {av.x, av.y, av.z, av.w};
    #pragma unroll
    for (int j = 0; j < 4; j++){
      int k = k4 * 4 + j;
      float ty = as[j] * scl[k] + shl[k];
      float y = (ty >= 0.f) ? ty : al * ty;
      const float* w = &W2l[k][c0];
      float4 wa = *(const float4*)(w);
      float4 wb = *(const float4*)(w + 4);
      acc[0] = fmaf(y, wa.x, acc[0]);
      acc[1] = fmaf(y, wa.y, acc[1]);
      acc[2] = fmaf(y, wa.z, acc[2]);
      acc[3] = fmaf(y, wa.w, acc[3]);
      acc[4] = fmaf(y, wb.x, acc[4]);
      acc[5] = fmaf(y, wb.y, acc[5]);
      acc[6] = fmaf(y, wb.z, acc[6]);
      acc[7] = fmaf(y, wb.w, acc[7]);
    }
  }
  float* p = h2 + (size_t)row * LAT + c0;
  *(float4*)(p)     = make_float4(acc[0], acc[1], acc[2], acc[3]);
  *(float4*)(p + 4) = make_float4(acc[4], acc[5], acc[6], acc[7]);
}

// ---------- final: out = bn2(agg2) + xin ----------
__global__ void k_final(const float* __restrict__ agg2, const float* __restrict__ scale,
                        const float* __restrict__ shift, const float* __restrict__ xin,
                        float* __restrict__ out, int n){
  int i = blockIdx.x * blockDim.x + threadIdx.x; // over n*LAT/4 float4s
  int total = n * (LAT / 4);
  if (i >= total) return;
  float4 a = ((const float4*)agg2)[i];
  float4 xi = ((const float4*)xin)[i];
  int f = (i * 4) & (LAT - 1);
  float4 o;
  o.x = a.x * scale[f+0] + shift[f+0] + xi.x;
  o.y = a.y * scale[f+1] + shift[f+1] + xi.y;
  o.z = a.z * scale[f+2] + shift[f+2] + xi.z;
  o.w = a.w * scale[f+3] + shift[f+3] + xi.w;
  ((float4*)out)[i] = o;
}

extern "C" void kernel_launch(void* const* d_in, const int* in_sizes, int n_in,
                              void* d_out, int out_size, void* d_ws, size_t ws_size,
                              hipStream_t stream){
  const float* x   = (const float*)d_in[0];
  const int*   ei  = (const int*)d_in[1];
  const float* ew  = (const float*)d_in[2];
  const float* W1  = (const float*)d_in[3];
  const float* g1  = (const float*)d_in[5];
  const float* be1 = (const float*)d_in[6];
  const float* W2  = (const float*)d_in[7];
  const float* g2  = (const float*)d_in[9];
  const float* be2 = (const float*)d_in[10];
  const float* pa  = (const float*)d_in[11];
  const float* Wr  = (const float*)d_in[12];
  const float* br  = (const float*)d_in[13];
  float* out = (float*)d_out;

  const int N = in_sizes[0] / IN_DIM;
  const int E = in_sizes[2];

  // workspace layout (256B aligned)
  char* ws = (char*)d_ws;
  size_t o = 0;
  auto alloc = [&](size_t bytes)->char*{
    char* p = ws + o;
    o = (o + bytes + 255) & ~(size_t)255;
    return p;
  };
  float* deg   = (float*)alloc((size_t)N * 4);      // becomes dinv
  int*   cnt   = (int*)  alloc((size_t)N * 4);
  int*   offs  = (int*)  alloc((size_t)N * 4);
  int*   cur   = (int*)  alloc((size_t)N * 4);
  int*   bsum  = (int*)  alloc(64 * 4);
  float* stats = (float*)alloc(192 * 4);  // sums1[64] sqs1[64] sums2[32] sqs2[32]
  float* coef  = (float*)alloc(192 * 4);  // scale1[64] shift1[64] scale2[32] shift2[32]
  int*   srcs  = (int*)  alloc((size_t)E * 4);
  float* vals  = (float*)alloc((size_t)E * 4);
  float* bufA  = (float*)alloc((size_t)N * HID * 4); // h1, then h2
  float* bufB  = (float*)alloc((size_t)N * HID * 4); // agg1, then agg2
  float* xin   = (float*)alloc((size_t)N * LAT * 4);

  float* sums1 = stats, *sqs1 = stats + 64, *sums2 = stats + 128, *sqs2 = stats + 160;
  float* sc1 = coef, *sh1 = coef + 64, *sc2 = coef + 128, *sh2 = coef + 160;

  const int NB = cdiv(N, 2048);

  k_init<<<cdiv(N, THREADS), THREADS, 0, stream>>>(deg, cnt, stats, N);
  k_count<<<cdiv(E, THREADS), THREADS, 0, stream>>>(ei, ew, deg, cnt, E);
  k_dinv<<<cdiv(N, THREADS), THREADS, 0, stream>>>(deg, N);
  k_scan1<<<NB, 256, 0, stream>>>(cnt, offs, bsum, N);
  k_scan2<<<1, 64, 0, stream>>>(bsum, NB);
  k_scan3<<<cdiv(N, THREADS), THREADS, 0, stream>>>(offs, cur, bsum, N);
  k_fill<<<cdiv(E, THREADS), THREADS, 0, stream>>>(ei, ew, deg, cur, srcs, vals, E);

  k_gemm1<<<cdiv(N, 64), G1_THREADS, 0, stream>>>(x, W1, Wr, br, bufA, xin, N);
  k_agg<HID><<<cdiv(N * HID, THREADS), THREADS, 0, stream>>>(bufA, offs, cnt, srcs, vals, deg, bufB, N);
  k_bnstats<HID><<<256, 256, 0, stream>>>(bufB, sums1, sqs1, N);
  k_bnfin<<<1, 64, 0, stream>>>(sums1, sqs1, g1, be1, sc1, sh1, N, HID);
  k_gemm2<<<cdiv(N, 64), THREADS, 0, stream>>>(bufB, sc1, sh1, pa, W2, bufA, N);
  k_agg<LAT><<<cdiv(N * LAT, THREADS), THREADS, 0, stream>>>(bufA, offs, cnt, srcs, vals, deg, bufB, N);
  k_bnstats<LAT><<<256, 256, 0, stream>>>(bufB, sums2, sqs2, N);
  k_bnfin<<<1, 32, 0, stream>>>(sums2, sqs2, g2, be2, sc2, sh2, N, LAT);
  k_final<<<cdiv(N * LAT / 4, THREADS), THREADS, 0, stream>>>(bufB, sc2, sh2, xin, out, N);
}

// Round 6
// 742.505 us; speedup vs baseline: 1.2686x; 1.0134x over previous
//
#include <hip/hip_runtime.h>

#define IN_DIM 256
#define HID 64
#define LAT 32
#define EPS 1e-5f
#define THREADS 256

static inline int cdiv(int a, int b){ return (a + b - 1) / b; }

// ---------- init: deg=1 (self loop), cnt=0, stats=0 ----------
__global__ void k_init(float* __restrict__ deg, int* __restrict__ cnt,
                       float* __restrict__ stats, int n){
  int i = blockIdx.x * blockDim.x + threadIdx.x;
  if (i < n){ deg[i] = 1.0f; cnt[i] = 0; }
  if (i < 192) stats[i] = 0.0f;
}

// ---------- degree + in-edge count ----------
__global__ void k_count(const int* __restrict__ ei, const float* __restrict__ ew,
                        float* __restrict__ deg, int* __restrict__ cnt, int E){
  int e = blockIdx.x * blockDim.x + threadIdx.x;
  if (e >= E) return;
  int c = ei[E + e];
  atomicAdd(&deg[c], ew[e]);
  atomicAdd(&cnt[c], 1);
}

// ---------- exclusive scan of cnt -> offs ----------
__global__ void k_scan1(const int* __restrict__ cnt, int* __restrict__ offs,
                        int* __restrict__ bsum, int n){
  __shared__ int lds[256];
  int t = threadIdx.x, b = blockIdx.x;
  int base = b * 2048 + t * 8;
  int v[8]; int s = 0;
  #pragma unroll
  for (int k = 0; k < 8; k++){ int idx = base + k; v[k] = (idx < n) ? cnt[idx] : 0; s += v[k]; }
  lds[t] = s; __syncthreads();
  for (int d = 1; d < 256; d <<= 1){
    int xv = (t >= d) ? lds[t - d] : 0;
    __syncthreads();
    lds[t] += xv;
    __syncthreads();
  }
  int excl = lds[t] - s;
  #pragma unroll
  for (int k = 0; k < 8; k++){ int idx = base + k; if (idx < n) offs[idx] = excl; excl += v[k]; }
  if (t == 0) bsum[b] = lds[255];
}

__global__ void k_scan2(int* __restrict__ bsum, int nb){
  __shared__ int lds[64];
  int t = threadIdx.x;
  int s = (t < nb) ? bsum[t] : 0;
  lds[t] = s; __syncthreads();
  for (int d = 1; d < 64; d <<= 1){
    int xv = (t >= d) ? lds[t - d] : 0;
    __syncthreads();
    lds[t] += xv;
    __syncthreads();
  }
  if (t < nb) bsum[t] = lds[t] - s;
}

// ---------- scan3 + dinv fused ----------
__global__ void k_scan3(int* __restrict__ offs, int* __restrict__ cur,
                        const int* __restrict__ bsum, float* __restrict__ deg, int n){
  int i = blockIdx.x * blockDim.x + threadIdx.x;
  if (i >= n) return;
  int o = offs[i] + bsum[i >> 11];
  offs[i] = o; cur[i] = o;
  deg[i] = rsqrtf(deg[i]);
}

// ---------- fill CSR, packed 8B edge records ----------
__global__ void k_fill(const int* __restrict__ ei, const float* __restrict__ ew,
                       const float* __restrict__ dinv, int* __restrict__ cur,
                       int2* __restrict__ edges, int E){
  int e = blockIdx.x * blockDim.x + threadIdx.x;
  if (e >= E) return;
  int r = ei[e], c = ei[E + e];
  int pos = atomicAdd(&cur[c], 1);
  edges[pos] = make_int2(r, __float_as_int(dinv[r] * ew[e] * dinv[c]));
}

// ---------- fused GEMM1: h1 = x@W1 ; xin = x@Wr + br ----------
// 2-D thread tiling: 384 thr = 12 colgroups(8 cols) x 32 rowgroups(4 rows),
// BM=128, Kc=64. x staged TRANSPOSED in LDS (1 b128 -> 4 rows).
// Per k: 3 ds_read_b128 (36cy) vs 32 FMA (64cy) -> VALU-bound.
#define G1_THREADS 384
#define G1_BM 128
#define G1_KC 64
__global__ __launch_bounds__(G1_THREADS, 2) void k_gemm1(
    const float* __restrict__ x, const float* __restrict__ W1,
    const float* __restrict__ Wr, const float* __restrict__ br,
    float* __restrict__ h1, float* __restrict__ xin, int n){
  __shared__ float Xl[G1_KC][132];   // 33792 B (pad 132: b128-aligned, low conflict)
  __shared__ float Wl[G1_KC][96];    // 24576 B
  int t = threadIdx.x;
  int cg = t >> 5;          // 0..11 -> col group (8 cols)
  int rg = t & 31;          // 0..31 -> row group (4 rows)
  int row0 = blockIdx.x * G1_BM;
  int c0 = cg * 8;
  float acc[4][8];
  #pragma unroll
  for (int i = 0; i < 4; i++)
    #pragma unroll
    for (int j = 0; j < 8; j++) acc[i][j] = 0.f;

  for (int kc = 0; kc < IN_DIM; kc += G1_KC){
    // stage W1 chunk: 64x64 = 1024 f4
    for (int i = t; i < 1024; i += G1_THREADS){
      int k = i >> 4, c = (i & 15) << 2;
      *(float4*)&Wl[k][c] = *(const float4*)&W1[(size_t)(kc + k) * HID + c];
    }
    // stage Wr chunk: 64x32 = 512 f4
    for (int i = t; i < 512; i += G1_THREADS){
      int k = i >> 3, c = (i & 7) << 2;
      *(float4*)&Wl[k][64 + c] = *(const float4*)&Wr[(size_t)(kc + k) * LAT + c];
    }
    // stage x transposed: 128 rows x 64 k = 2048 f4
    for (int i = t; i < 2048; i += G1_THREADS){
      int r = i >> 4, k4 = i & 15;
      int grow = row0 + r;
      float4 v = (grow < n) ? *(const float4*)&x[(size_t)grow * IN_DIM + kc + (k4 << 2)]
                            : make_float4(0.f, 0.f, 0.f, 0.f);
      int lk = k4 << 2;
      Xl[lk + 0][r] = v.x; Xl[lk + 1][r] = v.y;
      Xl[lk + 2][r] = v.z; Xl[lk + 3][r] = v.w;
    }
    __syncthreads();

    #pragma unroll 8
    for (int lk = 0; lk < G1_KC; lk++){
      float4 xv = *(const float4*)&Xl[lk][rg << 2];
      float4 wa = *(const float4*)&Wl[lk][c0];
      float4 wb = *(const float4*)&Wl[lk][c0 + 4];
      float xs[4] = {xv.x, xv.y, xv.z, xv.w};
      float wsv[8] = {wa.x, wa.y, wa.z, wa.w, wb.x, wb.y, wb.z, wb.w};
      #pragma unroll
      for (int i = 0; i < 4; i++)
        #pragma unroll
        for (int j = 0; j < 8; j++)
          acc[i][j] = fmaf(xs[i], wsv[j], acc[i][j]);
    }
    __syncthreads();
  }

  // epilogue: cols 0..63 -> h1, 64..95 -> xin (+br)
  #pragma unroll
  for (int i = 0; i < 4; i++){
    int row = row0 + (rg << 2) + i;
    if (row >= n) break;
    if (cg < 8){
      float* p = h1 + (size_t)row * HID + c0;
      *(float4*)(p)     = make_float4(acc[i][0], acc[i][1], acc[i][2], acc[i][3]);
      *(float4*)(p + 4) = make_float4(acc[i][4], acc[i][5], acc[i][6], acc[i][7]);
    } else {
      int cb = c0 - 64;
      float* p = xin + (size_t)row * LAT + cb;
      *(float4*)(p)     = make_float4(acc[i][0] + br[cb+0], acc[i][1] + br[cb+1],
                                      acc[i][2] + br[cb+2], acc[i][3] + br[cb+3]);
      *(float4*)(p + 4) = make_float4(acc[i][4] + br[cb+4], acc[i][5] + br[cb+5],
                                      acc[i][6] + br[cb+6], acc[i][7] + br[cb+7]);
    }
  }
}

// ---------- aggregation with packed edges ----------
template<int F>
__global__ void k_agg(const float* __restrict__ h, const int* __restrict__ offs,
                      const int* __restrict__ cnt, const int2* __restrict__ edges,
                      const float* __restrict__ dinv, float* __restrict__ out, int n){
  int gt = blockIdx.x * blockDim.x + threadIdx.x;
  int node = gt / F;
  int lane = gt & (F - 1);
  if (node >= n) return;
  float di = dinv[node];
  float acc = h[(size_t)node * F + lane] * (di * di);
  int j = offs[node];
  int e = j + cnt[node];
  for (; j + 3 < e; j += 4){
    int2 e0 = edges[j], e1 = edges[j+1], e2 = edges[j+2], e3 = edges[j+3];
    acc = fmaf(h[(size_t)e0.x * F + lane], __int_as_float(e0.y), acc);
    acc = fmaf(h[(size_t)e1.x * F + lane], __int_as_float(e1.y), acc);
    acc = fmaf(h[(size_t)e2.x * F + lane], __int_as_float(e2.y), acc);
    acc = fmaf(h[(size_t)e3.x * F + lane], __int_as_float(e3.y), acc);
  }
  for (; j < e; j++){
    int2 ee = edges[j];
    acc = fmaf(h[(size_t)ee.x * F + lane], __int_as_float(ee.y), acc);
  }
  out[(size_t)node * F + lane] = acc;
}

// ---------- batchnorm stats ----------
template<int F>
__global__ void k_bnstats(const float* __restrict__ a, float* __restrict__ sums,
                          float* __restrict__ sqs, int n){
  __shared__ float ls[256], lq[256];
  int t = threadIdx.x;
  int f = t & (F - 1);
  const int rpb = 256 / F;
  int r = blockIdx.x * rpb + t / F;
  int stride = gridDim.x * rpb;
  float s = 0.f, q = 0.f;
  for (; r < n; r += stride){
    float v = a[(size_t)r * F + f];
    s += v; q += v * v;
  }
  ls[t] = s; lq[t] = q; __syncthreads();
  if (t < F){
    for (int j = t + F; j < 256; j += F){ s += ls[j]; q += lq[j]; }
    atomicAdd(&sums[f], s);
    atomicAdd(&sqs[f], q);
  }
}

// ---------- finalize BN affine (conv bias cancels in BN) ----------
__global__ void k_bnfin(const float* __restrict__ sums, const float* __restrict__ sqs,
                        const float* __restrict__ g, const float* __restrict__ be,
                        float* __restrict__ scale, float* __restrict__ shift,
                        int n, int F){
  int f = threadIdx.x;
  if (f >= F) return;
  float inv_n = 1.0f / (float)n;
  float mean = sums[f] * inv_n;
  float var = sqs[f] * inv_n - mean * mean;
  float sc = g[f] * rsqrtf(var + EPS);
  scale[f] = sc;
  shift[f] = be[f] - mean * sc;
}

// ---------- fused BN1+PReLU+GEMM2: h2 = prelu(bn(agg1)) @ W2 ----------
// Same 2-D tiling: 128 thr = 4 cg(8 cols) x 32 rg(4 rows), BM=128, Kc=32.
// BN+PReLU applied during transpose-staging.
#define G2_THREADS 128
#define G2_BM 128
#define G2_KC 32
__global__ __launch_bounds__(G2_THREADS, 2) void k_gemm2(
    const float* __restrict__ agg1, const float* __restrict__ scale,
    const float* __restrict__ shift, const float* __restrict__ prelu_a,
    const float* __restrict__ W2, float* __restrict__ h2, int n){
  __shared__ float Yl[G2_KC][132];   // 16896 B
  __shared__ float Wl[HID][LAT];     // 8192 B
  int t = threadIdx.x;
  int cg = t >> 5;          // 0..3
  int rg = t & 31;          // 0..31
  int row0 = blockIdx.x * G2_BM;
  int c0 = cg * 8;
  float al = prelu_a[0];
  // stage W2 fully: 512 f4
  for (int i = t; i < 512; i += G2_THREADS){
    int k = i >> 3, c = (i & 7) << 2;
    *(float4*)&Wl[k][c] = *(const float4*)&W2[(size_t)k * LAT + c];
  }
  float acc[4][8];
  #pragma unroll
  for (int i = 0; i < 4; i++)
    #pragma unroll
    for (int j = 0; j < 8; j++) acc[i][j] = 0.f;

  for (int kc = 0; kc < HID; kc += G2_KC){
    __syncthreads();  // Wl ready (1st iter) / prev compute done reading Yl
    // stage y transposed: 128 rows x 32 k = 1024 f4
    for (int i = t; i < 1024; i += G2_THREADS){
      int r = i >> 3, k4 = i & 7;
      int grow = row0 + r;
      int gk = kc + (k4 << 2);
      float4 v = (grow < n) ? *(const float4*)&agg1[(size_t)grow * HID + gk]
                            : make_float4(0.f, 0.f, 0.f, 0.f);
      float4 sc = *(const float4*)&scale[gk];
      float4 sh = *(const float4*)&shift[gk];
      float y0 = v.x * sc.x + sh.x; y0 = (y0 >= 0.f) ? y0 : al * y0;
      float y1 = v.y * sc.y + sh.y; y1 = (y1 >= 0.f) ? y1 : al * y1;
      float y2 = v.z * sc.z + sh.z; y2 = (y2 >= 0.f) ? y2 : al * y2;
      float y3 = v.w * sc.w + sh.w; y3 = (y3 >= 0.f) ? y3 : al * y3;
      int lk = k4 << 2;
      Yl[lk + 0][r] = y0; Yl[lk + 1][r] = y1;
      Yl[lk + 2][r] = y2; Yl[lk + 3][r] = y3;
    }
    __syncthreads();
    #pragma unroll 8
    for (int lk = 0; lk < G2_KC; lk++){
      float4 yv = *(const float4*)&Yl[lk][rg << 2];
      float4 wa = *(const float4*)&Wl[kc + lk][c0];
      float4 wb = *(const float4*)&Wl[kc + lk][c0 + 4];
      float ys[4] = {yv.x, yv.y, yv.z, yv.w};
      float wsv[8] = {wa.x, wa.y, wa.z, wa.w, wb.x, wb.y, wb.z, wb.w};
      #pragma unroll
      for (int i = 0; i < 4; i++)
        #pragma unroll
        for (int j = 0; j < 8; j++)
          acc[i][j] = fmaf(ys[i], wsv[j], acc[i][j]);
    }
  }

  #pragma unroll
  for (int i = 0; i < 4; i++){
    int row = row0 + (rg << 2) + i;
    if (row >= n) break;
    float* p = h2 + (size_t)row * LAT + c0;
    *(float4*)(p)     = make_float4(acc[i][0], acc[i][1], acc[i][2], acc[i][3]);
    *(float4*)(p + 4) = make_float4(acc[i][4], acc[i][5], acc[i][6], acc[i][7]);
  }
}

// ---------- final: out = bn2(agg2) + xin ----------
__global__ void k_final(const float* __restrict__ agg2, const float* __restrict__ scale,
                        const float* __restrict__ shift, const float* __restrict__ xin,
                        float* __restrict__ out, int n){
  int i = blockIdx.x * blockDim.x + threadIdx.x;
  int total = n * (LAT / 4);
  if (i >= total) return;
  float4 a = ((const float4*)agg2)[i];
  float4 xi = ((const float4*)xin)[i];
  int f = (i * 4) & (LAT - 1);
  float4 o;
  o.x = a.x * scale[f+0] + shift[f+0] + xi.x;
  o.y = a.y * scale[f+1] + shift[f+1] + xi.y;
  o.z = a.z * scale[f+2] + shift[f+2] + xi.z;
  o.w = a.w * scale[f+3] + shift[f+3] + xi.w;
  ((float4*)out)[i] = o;
}

extern "C" void kernel_launch(void* const* d_in, const int* in_sizes, int n_in,
                              void* d_out, int out_size, void* d_ws, size_t ws_size,
                              hipStream_t stream){
  const float* x   = (const float*)d_in[0];
  const int*   ei  = (const int*)d_in[1];
  const float* ew  = (const float*)d_in[2];
  const float* W1  = (const float*)d_in[3];
  const float* g1  = (const float*)d_in[5];
  const float* be1 = (const float*)d_in[6];
  const float* W2  = (const float*)d_in[7];
  const float* g2  = (const float*)d_in[9];
  const float* be2 = (const float*)d_in[10];
  const float* pa  = (const float*)d_in[11];
  const float* Wr  = (const float*)d_in[12];
  const float* br  = (const float*)d_in[13];
  float* out = (float*)d_out;

  const int N = in_sizes[0] / IN_DIM;
  const int E = in_sizes[2];

  char* ws = (char*)d_ws;
  size_t o = 0;
  auto alloc = [&](size_t bytes)->char*{
    char* p = ws + o;
    o = (o + bytes + 255) & ~(size_t)255;
    return p;
  };
  float* deg   = (float*)alloc((size_t)N * 4);      // becomes dinv
  int*   cnt   = (int*)  alloc((size_t)N * 4);
  int*   offs  = (int*)  alloc((size_t)N * 4);
  int*   cur   = (int*)  alloc((size_t)N * 4);
  int*   bsum  = (int*)  alloc(64 * 4);
  float* stats = (float*)alloc(192 * 4);
  float* coef  = (float*)alloc(192 * 4);
  int2*  edges = (int2*) alloc((size_t)E * 8);
  float* bufA  = (float*)alloc((size_t)N * HID * 4); // h1, then h2
  float* bufB  = (float*)alloc((size_t)N * HID * 4); // agg1, then agg2
  float* xin   = (float*)alloc((size_t)N * LAT * 4);

  float* sums1 = stats, *sqs1 = stats + 64, *sums2 = stats + 128, *sqs2 = stats + 160;
  float* sc1 = coef, *sh1 = coef + 64, *sc2 = coef + 128, *sh2 = coef + 160;

  const int NB = cdiv(N, 2048);

  k_init<<<cdiv(N, THREADS), THREADS, 0, stream>>>(deg, cnt, stats, N);
  k_count<<<cdiv(E, THREADS), THREADS, 0, stream>>>(ei, ew, deg, cnt, E);
  k_scan1<<<NB, 256, 0, stream>>>(cnt, offs, bsum, N);
  k_scan2<<<1, 64, 0, stream>>>(bsum, NB);
  k_scan3<<<cdiv(N, THREADS), THREADS, 0, stream>>>(offs, cur, bsum, deg, N);
  k_fill<<<cdiv(E, THREADS), THREADS, 0, stream>>>(ei, ew, deg, cur, edges, E);

  k_gemm1<<<cdiv(N, G1_BM), G1_THREADS, 0, stream>>>(x, W1, Wr, br, bufA, xin, N);
  k_agg<HID><<<cdiv(N * HID, THREADS), THREADS, 0, stream>>>(bufA, offs, cnt, edges, deg, bufB, N);
  k_bnstats<HID><<<256, 256, 0, stream>>>(bufB, sums1, sqs1, N);
  k_bnfin<<<1, 64, 0, stream>>>(sums1, sqs1, g1, be1, sc1, sh1, N, HID);
  k_gemm2<<<cdiv(N, G2_BM), G2_THREADS, 0, stream>>>(bufB, sc1, sh1, pa, W2, bufA, N);
  k_agg<LAT><<<cdiv(N * LAT, THREADS), THREADS, 0, stream>>>(bufA, offs, cnt, edges, deg, bufB, N);
  k_bnstats<LAT><<<256, 256, 0, stream>>>(bufB, sums2, sqs2, N);
  k_bnfin<<<1, 32, 0, stream>>>(sums2, sqs2, g2, be2, sc2, sh2, N, LAT);
  k_final<<<cdiv(N * LAT / 4, THREADS), THREADS, 0, stream>>>(bufB, sc2, sh2, xin, out, N);
}